// Round 18
// baseline (1805.386 us; speedup 1.0000x reference)
//
#include <hip/hip_runtime.h>

#define SEPS 1e-10f

typedef float v2f __attribute__((ext_vector_type(2)));

__device__ __forceinline__ float fast_rcp(float x) { return __builtin_amdgcn_rcpf(x); }
__device__ __forceinline__ float fast_exp(float x) { return __expf(x); }
__device__ __forceinline__ float fast_sigmoid(float x) {
    return fast_rcp(1.0f + fast_exp(-x));
}
__device__ __forceinline__ v2f splat2(float x) { v2f r; r.x = x; r.y = x; return r; }

// r14 LDS-broadcast structure with ONE change: waves_per_eu(4,4).
// r14's failure was spills, not the LDS mechanism: ds_read weights land in
// VGPRs (+~40 pressure vs SGPR s_loads) while (4,8) capped arch VGPRs at 64
// -> accumulators spilled to scratch (FETCH 3.3GB, VALUBusy 8%). (4,4) caps
// at 128; peak live ~93 fits. SGPR 96->48 in r14 confirmed the weight stream
// did leave the scalar pipe — this round re-tests that mechanism with an
// adequate register budget.
__global__ __launch_bounds__(256)
__attribute__((amdgpu_waves_per_eu(4, 4)))
void sinkhorn_mlp_kernel(
    const float* __restrict__ margins,
    const float* __restrict__ W1, const float* __restrict__ b1,
    const float* __restrict__ W2, const float* __restrict__ b2,
    const float* __restrict__ W3, const float* __restrict__ b3,
    const float* __restrict__ W4, const float* __restrict__ b4,
    float* __restrict__ out_mus, float* __restrict__ out_V, int n)
{
    __shared__ __align__(16) float sW1T[64][8];   // [k][0..5]=W1[i][k], [6]=b1[k], [7]=pad
    __shared__ __align__(16) float sW2[64][32];   // row-major, row = k
    __shared__ __align__(16) float sW3[32][16];
    __shared__ __align__(16) float sW4[16][12];   // [k][0..8]=W4[k][j], pad 3
    __shared__ __align__(16) float sB2[32];
    __shared__ __align__(16) float sB3[16];
    __shared__ __align__(16) float sB4[12];

    const int tid = threadIdx.x;

    // ---------------- one-time weight staging ----------------
    if (tid < 128) {                       // W1T + b1: 64 rows x 8 floats
        int k = tid >> 1;
        int h4 = (tid & 1) * 4;
        float4 v;
        float e[4];
#pragma unroll
        for (int q = 0; q < 4; ++q) {
            int i = h4 + q;
            e[q] = (i < 6) ? W1[i * 64 + k] : ((i == 6) ? b1[k] : 0.0f);
        }
        v.x = e[0]; v.y = e[1]; v.z = e[2]; v.w = e[3];
        *reinterpret_cast<float4*>(&sW1T[k][h4]) = v;
    }
    {                                      // W2: 2048 floats = 512 float4
        const float4* src = reinterpret_cast<const float4*>(W2);
        float4* dst = reinterpret_cast<float4*>(&sW2[0][0]);
        dst[tid] = src[tid];
        dst[tid + 256] = src[tid + 256];
    }
    if (tid < 128) {                       // W3: 512 floats = 128 float4
        reinterpret_cast<float4*>(&sW3[0][0])[tid] =
            reinterpret_cast<const float4*>(W3)[tid];
    }
    if (tid < 16) {                        // W4: 16 rows x 9 (+3 pad)
#pragma unroll
        for (int j = 0; j < 9; ++j) sW4[tid][j] = W4[tid * 9 + j];
        sW4[tid][9] = 0.f; sW4[tid][10] = 0.f; sW4[tid][11] = 0.f;
    }
    if (tid < 32) sB2[tid] = b2[tid];
    if (tid < 16) sB3[tid] = b3[tid];
    if (tid < 12) sB4[tid] = (tid < 9) ? b4[tid] : 0.0f;
    __syncthreads();

    // ---------------- grid-stride over 256-row chunks ----------------
    for (size_t base = (size_t)blockIdx.x * 256; base < (size_t)n;
         base += (size_t)gridDim.x * 256) {
        size_t r = base + tid;
        bool ok = r < (size_t)n;
        size_t rc = ok ? r : 0;

        // ---- margins (6 floats, 8B-aligned) ----
        const float2* mp = reinterpret_cast<const float2*>(margins + rc * 6);
        float2 mv0 = mp[0], mv1 = mp[1], mv2 = mp[2];
        float m0 = mv0.x, m1 = mv0.y, m2 = mv1.x, m3 = mv1.y, m4 = mv2.x, m5 = mv2.y;

        // ---- layers 1+2 fused, j packed (h2p[jp] covers j=2jp,2jp+1) ----
        v2f h2p[16];
        const v2f* b2v = reinterpret_cast<const v2f*>(sB2);
#pragma unroll
        for (int jp = 0; jp < 16; ++jp) h2p[jp] = b2v[jp];

#pragma unroll 2
        for (int k = 0; k < 64; ++k) {
            const float* w1r = sW1T[k];           // uniform ds_read (broadcast)
            float t = w1r[6];
            t = fmaf(m0, w1r[0], t);
            t = fmaf(m1, w1r[1], t);
            t = fmaf(m2, w1r[2], t);
            t = fmaf(m3, w1r[3], t);
            t = fmaf(m4, w1r[4], t);
            t = fmaf(m5, w1r[5], t);
            t = fmaxf(t, 0.0f);
            v2f tv = splat2(t);
            const v2f* w2r = reinterpret_cast<const v2f*>(sW2[k]);
#pragma unroll
            for (int jp = 0; jp < 16; ++jp)
                h2p[jp] = __builtin_elementwise_fma(tv, w2r[jp], h2p[jp]);
        }

        // ---- layer 3 fused, packed ----
        v2f h3p[8];
        const v2f* b3v = reinterpret_cast<const v2f*>(sB3);
#pragma unroll
        for (int jp = 0; jp < 8; ++jp) h3p[jp] = b3v[jp];
#pragma unroll
        for (int k = 0; k < 32; ++k) {
            float hk = (k & 1) ? h2p[k >> 1].y : h2p[k >> 1].x;
            float t = fmaxf(hk, 0.0f);
            v2f tv = splat2(t);
            const v2f* w3r = reinterpret_cast<const v2f*>(sW3[k]);
#pragma unroll
            for (int jp = 0; jp < 8; ++jp)
                h3p[jp] = __builtin_elementwise_fma(tv, w3r[jp], h3p[jp]);
        }

        // ---- layer 4 fused, scalar ----
        float pars[9];
        {
            const float4* b4v = reinterpret_cast<const float4*>(sB4);
            float4 bb0 = b4v[0], bb1 = b4v[1], bb2 = b4v[2];
            pars[0] = bb0.x; pars[1] = bb0.y; pars[2] = bb0.z; pars[3] = bb0.w;
            pars[4] = bb1.x; pars[5] = bb1.y; pars[6] = bb1.z; pars[7] = bb1.w;
            pars[8] = bb2.x;
        }
#pragma unroll
        for (int k = 0; k < 16; ++k) {
            float hk = (k & 1) ? h3p[k >> 1].y : h3p[k >> 1].x;
            float t = fmaxf(hk, 0.0f);
            const float4* w4r = reinterpret_cast<const float4*>(sW4[k]);
            float4 wa = w4r[0], wb = w4r[1], wc = w4r[2];
            pars[0] = fmaf(t, wa.x, pars[0]);
            pars[1] = fmaf(t, wa.y, pars[1]);
            pars[2] = fmaf(t, wa.z, pars[2]);
            pars[3] = fmaf(t, wa.w, pars[3]);
            pars[4] = fmaf(t, wb.x, pars[4]);
            pars[5] = fmaf(t, wb.y, pars[5]);
            pars[6] = fmaf(t, wb.z, pars[6]);
            pars[7] = fmaf(t, wb.w, pars[7]);
            pars[8] = fmaf(t, wc.x, pars[8]);
        }

        // ---- heads ----
        float p0 = fast_exp(pars[0]);
        float p1 = fast_exp(pars[1]);
        float p2 = fast_exp(pars[2]);
        float p3 = fast_exp(pars[3]);

        float A00 = p3 * p0, A01 = p3 * p1, A02 = p3 * p2;
        float A10 = p3 * p1, A11 = p3 * p0, A12 = p3 * p1;
        float A20 = p3 * p2, A21 = p3 * p1, A22 = p3 * p0;

        float sm0 = fast_sigmoid(pars[4]);
        float sm1 = fast_sigmoid(pars[5]);
        float sf0 = fast_sigmoid(pars[6]);
        float sf1 = fast_sigmoid(pars[7]);
        float V   = fast_exp(pars[8]);

        float rc0 = m0 * sm0, rc1 = m1 * sm1, rc2 = m2;
        float cc0 = m3 * sf0, cc1 = m4 * sf1, cc2 = m5;
        float mum0_0 = m0 * (1.0f - sm0);
        float mum0_1 = m1 * (1.0f - sm1);
        float mu0f_0 = m3 * (1.0f - sf0);
        float mu0f_1 = m4 * (1.0f - sf1);

        // ---- Sinkhorn: 10 iterations (register-resident 3x3) ----
#pragma unroll
        for (int it = 0; it < 10; ++it) {
            float f0 = rc0 * fast_rcp(A00 + A01 + A02 + SEPS);
            float f1 = rc1 * fast_rcp(A10 + A11 + A12 + SEPS);
            float f2 = rc2 * fast_rcp(A20 + A21 + A22 + SEPS);
            A00 *= f0; A01 *= f0; A02 *= f0;
            A10 *= f1; A11 *= f1; A12 *= f1;
            A20 *= f2; A21 *= f2; A22 *= f2;
            float g0 = cc0 * fast_rcp(A00 + A10 + A20 + SEPS);
            float g1 = cc1 * fast_rcp(A01 + A11 + A21 + SEPS);
            float g2 = cc2 * fast_rcp(A02 + A12 + A22 + SEPS);
            A00 *= g0; A10 *= g0; A20 *= g0;
            A01 *= g1; A11 *= g1; A21 *= g1;
            A02 *= g2; A12 *= g2; A22 *= g2;
        }

        // ---- output: mus (4x4 row-major) then V ----
        if (ok) {
            float4* o = reinterpret_cast<float4*>(out_mus + r * 16);
            o[0] = make_float4(A00, A01, A02, mum0_0);
            o[1] = make_float4(A10, A11, A12, mum0_1);
            o[2] = make_float4(A20, A21, A22, 0.0f);
            o[3] = make_float4(mu0f_0, mu0f_1, 0.0f, 0.0f);
            out_V[r] = V;
        }
    }
}

extern "C" void kernel_launch(void* const* d_in, const int* in_sizes, int n_in,
                              void* d_out, int out_size, void* d_ws, size_t ws_size,
                              hipStream_t stream) {
    const float* margins = (const float*)d_in[0];
    const float* W1 = (const float*)d_in[1];
    const float* b1 = (const float*)d_in[2];
    const float* W2 = (const float*)d_in[3];
    const float* b2 = (const float*)d_in[4];
    const float* W3 = (const float*)d_in[5];
    const float* b3 = (const float*)d_in[6];
    const float* W4 = (const float*)d_in[7];
    const float* b4 = (const float*)d_in[8];

    int n = in_sizes[0] / 6;
    float* out_mus = (float*)d_out;
    float* out_V   = out_mus + (size_t)n * 16;

    dim3 block(256);
    dim3 grid(2048);   // grid-stride; resident 4 blocks/CU under (4,4)
    sinkhorn_mlp_kernel<<<grid, block, 0, stream>>>(
        margins, W1, b1, W2, b2, W3, b3, W4, b4, out_mus, out_V, n);
}

// Round 19
// 156.104 us; speedup vs baseline: 11.5653x; 11.5653x over previous
//
#include <hip/hip_runtime.h>

#define SEPS 1e-10f

typedef float v2f __attribute__((ext_vector_type(2)));

__device__ __forceinline__ float fast_rcp(float x) { return __builtin_amdgcn_rcpf(x); }
__device__ __forceinline__ float fast_exp(float x) { return __expf(x); }
__device__ __forceinline__ float fast_sigmoid(float x) {
    return fast_rcp(1.0f + fast_exp(-x));
}
__device__ __forceinline__ v2f splat2(float x) { v2f r; r.x = x; r.y = x; return r; }

// Prep kernel: repack W1 (+b1) and W4 into request-friendly layouts in d_ws.
//  W1T[64][8]: [k][0..5]=W1[i][k], [6]=b1[k], [7]=pad  (k-pair = 16 contiguous
//              floats -> 1-2 merged wide s_loads instead of 7 scattered ones)
//  W4T[16][12]: [k][0..8]=W4[k][j], pad 3              (row = 48B -> x8+x4)
__global__ void sinkhorn_prep_kernel(
    const float* __restrict__ W1, const float* __restrict__ b1,
    const float* __restrict__ W4, float* __restrict__ ws)
{
    int t = threadIdx.x;
    if (t < 64) {
#pragma unroll
        for (int i = 0; i < 6; ++i) ws[t * 8 + i] = W1[i * 64 + t];
        ws[t * 8 + 6] = b1[t];
        ws[t * 8 + 7] = 0.0f;
    } else if (t >= 64 && t < 80) {
        int k = t - 64;
#pragma unroll
        for (int j = 0; j < 9; ++j) ws[512 + k * 12 + j] = W4[k * 9 + j];
        ws[512 + k * 12 + 9]  = 0.0f;
        ws[512 + k * 12 + 10] = 0.0f;
        ws[512 + k * 12 + 11] = 0.0f;
    }
}

// r12 compute structure EXACTLY (185us rocprof best: rolled+unroll2 L1+L2,
// v2f-packed L2/L3, scalar L1/L4, (4,8)); only the weight ADDRESSING changes:
// W1/b1 and W4 come from the prep-repacked d_ws layouts. Theory: r12 is
// SMEM-request-rate-bound (~420 req/wave ~= the 185us wall at ~1 req/8cyc/CU);
// W1T collapses 7 scattered requests per 2k into 1-2 merged wide loads.
__global__ __launch_bounds__(256)
__attribute__((amdgpu_waves_per_eu(4, 8)))
void sinkhorn_mlp_kernel(
    const float* __restrict__ margins,
    const float* __restrict__ w1t,    // d_ws: W1T[64][8]
    const float* __restrict__ W2, const float* __restrict__ b2,
    const float* __restrict__ W3, const float* __restrict__ b3,
    const float* __restrict__ w4t,    // d_ws+512: W4T[16][12]
    const float* __restrict__ b4,
    float* __restrict__ out_mus, float* __restrict__ out_V, int n)
{
    int r = blockIdx.x * blockDim.x + threadIdx.x;
    if (r >= n) return;

    // ---- load margins (6 floats, 8B-aligned) ----
    const float2* mp = reinterpret_cast<const float2*>(margins + (size_t)r * 6);
    float2 mv0 = mp[0], mv1 = mp[1], mv2 = mp[2];
    float m0 = mv0.x, m1 = mv0.y, m2 = mv1.x, m3 = mv1.y, m4 = mv2.x, m5 = mv2.y;

    // ---- layers 1+2 fused, j packed in pairs: h2p[jp] covers j=2jp,2jp+1 ----
    v2f h2p[16];
    const v2f* b2v = reinterpret_cast<const v2f*>(b2);
#pragma unroll
    for (int jp = 0; jp < 16; ++jp) h2p[jp] = b2v[jp];

#pragma unroll 2
    for (int k = 0; k < 64; ++k) {
        const float* w1r = w1t + k * 8;   // contiguous [W1col..., b1, pad]
        float t = w1r[6];
        t = fmaf(m0, w1r[0], t);
        t = fmaf(m1, w1r[1], t);
        t = fmaf(m2, w1r[2], t);
        t = fmaf(m3, w1r[3], t);
        t = fmaf(m4, w1r[4], t);
        t = fmaf(m5, w1r[5], t);
        t = fmaxf(t, 0.0f);
        v2f tv = splat2(t);
        const v2f* w2r = reinterpret_cast<const v2f*>(W2 + k * 32);
#pragma unroll
        for (int jp = 0; jp < 16; ++jp)
            h2p[jp] = __builtin_elementwise_fma(tv, w2r[jp], h2p[jp]);
    }

    // ---- layer 3 fused, packed (W3 rows: 16 floats = 1 wide request) ----
    v2f h3p[8];
    const v2f* b3v = reinterpret_cast<const v2f*>(b3);
#pragma unroll
    for (int jp = 0; jp < 8; ++jp) h3p[jp] = b3v[jp];
#pragma unroll
    for (int k = 0; k < 32; ++k) {
        float hk = (k & 1) ? h2p[k >> 1].y : h2p[k >> 1].x;   // compile-time select
        float t = fmaxf(hk, 0.0f);
        v2f tv = splat2(t);
        const v2f* w3r = reinterpret_cast<const v2f*>(W3 + k * 16);
#pragma unroll
        for (int jp = 0; jp < 8; ++jp)
            h3p[jp] = __builtin_elementwise_fma(tv, w3r[jp], h3p[jp]);
    }

    // ---- layer 4 fused, scalar (padded 12-stride rows from prep) ----
    float pars[9];
#pragma unroll
    for (int j = 0; j < 9; ++j) pars[j] = b4[j];
#pragma unroll
    for (int k = 0; k < 16; ++k) {
        float hk = (k & 1) ? h3p[k >> 1].y : h3p[k >> 1].x;
        float t = fmaxf(hk, 0.0f);
        const float* w4r = w4t + k * 12;
#pragma unroll
        for (int j = 0; j < 9; ++j) pars[j] = fmaf(t, w4r[j], pars[j]);
    }

    // ---- heads ----
    float p0 = fast_exp(pars[0]);
    float p1 = fast_exp(pars[1]);
    float p2 = fast_exp(pars[2]);
    float p3 = fast_exp(pars[3]);

    float A00 = p3 * p0, A01 = p3 * p1, A02 = p3 * p2;
    float A10 = p3 * p1, A11 = p3 * p0, A12 = p3 * p1;
    float A20 = p3 * p2, A21 = p3 * p1, A22 = p3 * p0;

    float sm0 = fast_sigmoid(pars[4]);
    float sm1 = fast_sigmoid(pars[5]);
    float sf0 = fast_sigmoid(pars[6]);
    float sf1 = fast_sigmoid(pars[7]);
    float V   = fast_exp(pars[8]);

    float rc0 = m0 * sm0, rc1 = m1 * sm1, rc2 = m2;   // row targets
    float cc0 = m3 * sf0, cc1 = m4 * sf1, cc2 = m5;   // col targets
    float mum0_0 = m0 * (1.0f - sm0);
    float mum0_1 = m1 * (1.0f - sm1);
    float mu0f_0 = m3 * (1.0f - sf0);
    float mu0f_1 = m4 * (1.0f - sf1);

    // ---- Sinkhorn: 10 iterations (register-resident 3x3, scalar) ----
#pragma unroll
    for (int it = 0; it < 10; ++it) {
        float f0 = rc0 * fast_rcp(A00 + A01 + A02 + SEPS);
        float f1 = rc1 * fast_rcp(A10 + A11 + A12 + SEPS);
        float f2 = rc2 * fast_rcp(A20 + A21 + A22 + SEPS);
        A00 *= f0; A01 *= f0; A02 *= f0;
        A10 *= f1; A11 *= f1; A12 *= f1;
        A20 *= f2; A21 *= f2; A22 *= f2;
        float g0 = cc0 * fast_rcp(A00 + A10 + A20 + SEPS);
        float g1 = cc1 * fast_rcp(A01 + A11 + A21 + SEPS);
        float g2 = cc2 * fast_rcp(A02 + A12 + A22 + SEPS);
        A00 *= g0; A10 *= g0; A20 *= g0;
        A01 *= g1; A11 *= g1; A21 *= g1;
        A02 *= g2; A12 *= g2; A22 *= g2;
    }

    // ---- output: mus (4x4 row-major) then V ----
    float4* o = reinterpret_cast<float4*>(out_mus + (size_t)r * 16);
    o[0] = make_float4(A00, A01, A02, mum0_0);
    o[1] = make_float4(A10, A11, A12, mum0_1);
    o[2] = make_float4(A20, A21, A22, 0.0f);
    o[3] = make_float4(mu0f_0, mu0f_1, 0.0f, 0.0f);
    out_V[r] = V;
}

extern "C" void kernel_launch(void* const* d_in, const int* in_sizes, int n_in,
                              void* d_out, int out_size, void* d_ws, size_t ws_size,
                              hipStream_t stream) {
    const float* margins = (const float*)d_in[0];
    const float* W1 = (const float*)d_in[1];
    const float* b1 = (const float*)d_in[2];
    const float* W2 = (const float*)d_in[3];
    const float* b2 = (const float*)d_in[4];
    const float* W3 = (const float*)d_in[5];
    const float* b3 = (const float*)d_in[6];
    const float* W4 = (const float*)d_in[7];
    const float* b4 = (const float*)d_in[8];

    int n = in_sizes[0] / 6;
    float* out_mus = (float*)d_out;
    float* out_V   = out_mus + (size_t)n * 16;
    float* ws      = (float*)d_ws;   // needs 704 floats = 2816 B

    sinkhorn_prep_kernel<<<1, 256, 0, stream>>>(W1, b1, W4, ws);

    dim3 block(256);
    dim3 grid((n + 255) / 256);
    sinkhorn_mlp_kernel<<<grid, block, 0, stream>>>(
        margins, ws, W2, b2, W3, b3, ws + 512, b4, out_mus, out_V, n);
}